// Round 1
// 2429.376 us; speedup vs baseline: 1.2216x; 1.2216x over previous
//
#include <hip/hip_runtime.h>
#include <hip/hip_bf16.h>

#define BATCH 512
#define SEQ   128
#define EMB   768
#define NH    6
#define HDIM  256
#define CATD  1536
#define FFD   3072
#define NTOK  (BATCH*SEQ)
#define QKVLD 4608

typedef __attribute__((ext_vector_type(8))) short bfrag;   // 8 bf16 = 4 VGPRs
typedef __attribute__((ext_vector_type(4))) float f32x4;

// async 16B global->LDS; LDS dest is wave-uniform base + lane*16
__device__ __forceinline__ void gld_lds16(const void* g, void* l) {
  __builtin_amdgcn_global_load_lds(
      (const __attribute__((address_space(1))) unsigned int*)g,
      (__attribute__((address_space(3))) unsigned int*)l, 16, 0, 0);
}

__device__ __forceinline__ unsigned short f2bfu(float f) {
  union { __hip_bfloat16 h; unsigned short u; } c;
  c.h = __float2bfloat16(f);
  return c.u;
}

// ---------------- weight repack: fp32 [R][C] -> bf16 [C][R] -----------------
__device__ __forceinline__ void transpose64(const float* in, int C,
                                            __hip_bfloat16* out, int R,
                                            int r0, int c0) {
  __shared__ float tile[64][65];
  const int tx = threadIdx.x & 63;
  const int ty = threadIdx.x >> 6;
#pragma unroll
  for (int i = 0; i < 16; ++i) {
    const int r = ty + i * 4;
    tile[r][tx] = in[(size_t)(r0 + r) * C + c0 + tx];
  }
  __syncthreads();
#pragma unroll
  for (int i = 0; i < 16; ++i) {
    const int cc = ty + i * 4;
    out[(size_t)(c0 + cc) * R + r0 + tx] = __float2bfloat16(tile[tx][cc]);
  }
}

__global__ __launch_bounds__(256) void transpose_cast(const float* __restrict__ in,
                                                      __hip_bfloat16* __restrict__ out,
                                                      int R, int C) {
  transpose64(in, C, out, R, blockIdx.y * 64, blockIdx.x * 64);
}

// Wq/Wk/Wv [H][E][D] -> Wqkv_t [4608][768], row n = m*1536 + h*256 + d
__global__ __launch_bounds__(256) void repack_qkv(const float* __restrict__ Wq,
                                                  const float* __restrict__ Wk,
                                                  const float* __restrict__ Wv,
                                                  __hip_bfloat16* __restrict__ out) {
  const int z = blockIdx.z, m = z / NH, h = z % NH;
  const float* in = (m == 0 ? Wq : (m == 1 ? Wk : Wv)) + (size_t)h * EMB * HDIM;
  __hip_bfloat16* o = out + (size_t)(m * CATD + h * HDIM) * EMB;
  transpose64(in, HDIM, o, EMB, blockIdx.y * 64, blockIdx.x * 64);
}

// ---------------- LayerNorm: fp32 [rows][768] -> bf16 ----------------------
__global__ __launch_bounds__(256) void ln_k(const float* __restrict__ src,
                                            const float* __restrict__ gam,
                                            const float* __restrict__ bet,
                                            __hip_bfloat16* __restrict__ dst) {
  const int row = blockIdx.x * 4 + (threadIdx.x >> 6);
  const int l = threadIdx.x & 63;
  const float* x = src + (size_t)row * EMB;
  float4 v[3];
#pragma unroll
  for (int j = 0; j < 3; ++j) v[j] = *(const float4*)(x + j * 256 + l * 4);
  float s = 0.f, ss = 0.f;
#pragma unroll
  for (int j = 0; j < 3; ++j) {
    s  += v[j].x + v[j].y + v[j].z + v[j].w;
    ss += v[j].x * v[j].x + v[j].y * v[j].y + v[j].z * v[j].z + v[j].w * v[j].w;
  }
#pragma unroll
  for (int d = 1; d < 64; d <<= 1) { s += __shfl_xor(s, d, 64); ss += __shfl_xor(ss, d, 64); }
  const float mu = s * (1.f / EMB);
  const float var = ss * (1.f / EMB) - mu * mu;
  const float rs = rsqrtf(var + 1e-5f);
#pragma unroll
  for (int j = 0; j < 3; ++j) {
    float4 g4 = *(const float4*)(gam + j * 256 + l * 4);
    float4 b4 = *(const float4*)(bet + j * 256 + l * 4);
    ushort4 o;
    o.x = f2bfu((v[j].x - mu) * rs * g4.x + b4.x);
    o.y = f2bfu((v[j].y - mu) * rs * g4.y + b4.y);
    o.z = f2bfu((v[j].z - mu) * rs * g4.z + b4.z);
    o.w = f2bfu((v[j].w - mu) * rs * g4.w + b4.w);
    *(ushort4*)((unsigned short*)dst + (size_t)row * EMB + j * 256 + l * 4) = o;
  }
}

// ---------------- GEMM: C[M][N] = A[M][K](bf16) * Bt[N][K](bf16) -----------
// 256x256 tile, BK=64, 8 waves (2M x 4N), 512 threads, 128 KiB LDS dbuf.
// Staging is in MFMA-fragment order (chunk = 16 rows x 32 k in lane order),
// so global_load_lds dest is linear AND every ds_read_b128 is a contiguous
// 1 KiB wave read -> zero bank conflicts, no swizzle needed (T2-equivalent).
// 4 phases per K-tile: phase (s, m-half) = {2x global_load_lds issue,
// 8x ds_read_b128, setprio(1), 16 MFMA, setprio(0), barrier}.
// s=0 chunks of a buffer are dead after phase 1, so phases 2-3 prefetch tile
// kt+2's s=0 into the CURRENT buffer while phases 0-1 prefetch tile kt+1's
// s=1 into the other -> 6 loads stay in flight at the boundary: vmcnt(6),
// never drained in the main loop (T3+T4; T5 setprio on the MFMA clusters).
// MODE 0: C bf16 = acc ; MODE 1: C f32 = acc+bias+res ; MODE 2: bf16 relu(acc+bias)
#define PHASE(S, MH) do {                                                    \
    bfrag af[4], bv[4];                                                      \
    const char* Ab = cbuf + ((S)*16 + wm*8 + (MH)*4) * 1024 + l * 16;        \
    const char* Bb = cbuf + 32768 + ((S)*16 + wn*4) * 1024 + l * 16;         \
    _Pragma("unroll")                                                        \
    for (int i = 0; i < 4; ++i) af[i] = *(const bfrag*)(Ab + i * 1024);      \
    _Pragma("unroll")                                                        \
    for (int n = 0; n < 4; ++n) bv[n] = *(const bfrag*)(Bb + n * 1024);      \
    __builtin_amdgcn_s_setprio(1);                                          \
    _Pragma("unroll")                                                        \
    for (int i = 0; i < 4; ++i)                                              \
      _Pragma("unroll")                                                      \
      for (int n = 0; n < 4; ++n)                                            \
        acc[(MH)*4 + i][n] = __builtin_amdgcn_mfma_f32_16x16x32_bf16(        \
            af[i], bv[n], acc[(MH)*4 + i][n], 0, 0, 0);                      \
    __builtin_amdgcn_s_setprio(0);                                          \
  } while (0)

#define PH_END                                                \
  asm volatile("s_waitcnt lgkmcnt(0)" ::: "memory");          \
  asm volatile("s_barrier" ::: "memory")

#define STG(p, koff, dstoff) gld_lds16((p) + (koff), lds + (dstoff))

template <int MODE>
__global__ __launch_bounds__(512, 2)
void gemm_k(const __hip_bfloat16* __restrict__ A, const __hip_bfloat16* __restrict__ Bt,
            void* __restrict__ Cout, const float* __restrict__ bias,
            const float* __restrict__ res, int M, int N, int K) {
  __shared__ char lds[131072];          // 2 x (A 32KB + B 32KB); epilogue reuses
  const int tid = threadIdx.x;
  const int w = tid >> 6, l = tid & 63;
  const int l15 = l & 15, lq = l >> 4;
  const int wm = w >> 2, wn = w & 3;

  // XCD-aware bijective block swizzle (all grids divisible by 8)
  const int nwg = gridDim.x * gridDim.y;
  const int orig = blockIdx.y * gridDim.x + blockIdx.x;
  const int cpx = nwg >> 3;
  const int sw = (orig & 7) * cpx + (orig >> 3);
  const int n0 = (sw % gridDim.x) * 256;
  const int m0 = (sw / gridDim.x) * 256;

  const unsigned short* Au = (const unsigned short*)A;
  const unsigned short* Bu = (const unsigned short*)Bt;
  // per-lane staging sources; chunk rb covers rows rb*16+l15, lane part lq*8
  const unsigned short* pA_lo = Au + (size_t)(m0 + w * 16 + l15) * K + lq * 8;
  const unsigned short* pA_hi = Au + (size_t)(m0 + 128 + w * 16 + l15) * K + lq * 8;
  const unsigned short* pB_lo = Bu + (size_t)(n0 + w * 16 + l15) * K + lq * 8;
  const unsigned short* pB_hi = Bu + (size_t)(n0 + 128 + w * 16 + l15) * K + lq * 8;

  f32x4 acc[8][4];
#pragma unroll
  for (int i = 0; i < 8; ++i)
#pragma unroll
    for (int n = 0; n < 4; ++n) acc[i][n] = {0.f, 0.f, 0.f, 0.f};

  const int kIters = K >> 6;            // K/64, always >= 12 here

  // prologue: tile0 (s0+s1) -> buf0, tile1 s0 -> buf1
  STG(pA_lo, 0,  (0 + w) * 1024);
  STG(pA_hi, 0,  (8 + w) * 1024);
  STG(pB_lo, 0,  32768 + (0 + w) * 1024);
  STG(pB_hi, 0,  32768 + (8 + w) * 1024);
  STG(pA_lo, 32, (16 + w) * 1024);
  STG(pA_hi, 32, (24 + w) * 1024);
  STG(pB_lo, 32, 32768 + (16 + w) * 1024);
  STG(pB_hi, 32, 32768 + (24 + w) * 1024);
  STG(pA_lo, 64, 65536 + (0 + w) * 1024);
  STG(pA_hi, 64, 65536 + (8 + w) * 1024);
  STG(pB_lo, 64, 65536 + 32768 + (0 + w) * 1024);
  STG(pB_hi, 64, 65536 + 32768 + (8 + w) * 1024);

  for (int kt = 0; kt < kIters; ++kt) {
    const int cOff = (kt & 1) * 65536;
    const int nOff = cOff ^ 65536;
    const char* cbuf = lds + cOff;
    const bool pre1 = (kt + 1 < kIters);   // tile kt+1 s1 -> other buffer
    const bool pre2 = (kt + 2 < kIters);   // tile kt+2 s0 -> current buffer
    const int k1 = (kt + 1) * 64 + 32;
    const int k2 = (kt + 2) * 64;

    // ---- phase 0: s=0, rows lo ----
    if (pre1) {
      STG(pA_lo, k1, nOff + (16 + w) * 1024);
      STG(pB_lo, k1, nOff + 32768 + (16 + w) * 1024);
      asm volatile("s_waitcnt vmcnt(6)" ::: "memory");
    } else {
      asm volatile("s_waitcnt vmcnt(0)" ::: "memory");
    }
    asm volatile("s_barrier" ::: "memory");   // tile kt fully staged
    PHASE(0, 0);
    PH_END;
    // ---- phase 1: s=0, rows hi ----
    if (pre1) {
      STG(pA_hi, k1, nOff + (24 + w) * 1024);
      STG(pB_hi, k1, nOff + 32768 + (24 + w) * 1024);
    }
    PHASE(0, 1);
    PH_END;                                   // after this, cbuf s0 is dead
    // ---- phase 2: s=1, rows lo ----
    if (pre2) {
      STG(pA_lo, k2, cOff + (0 + w) * 1024);
      STG(pB_lo, k2, cOff + 32768 + (0 + w) * 1024);
    }
    PHASE(1, 0);
    PH_END;
    // ---- phase 3: s=1, rows hi ----
    if (pre2) {
      STG(pA_hi, k2, cOff + (8 + w) * 1024);
      STG(pB_hi, k2, cOff + 32768 + (8 + w) * 1024);
    }
    PHASE(1, 1);
    PH_END;                                   // cbuf s1 dead -> reusable next iter
  }

  // ---- epilogue: acc (+bias/relu/res) -> LDS -> coalesced stores ----
  float bcol[4];
  if (MODE != 0) {
#pragma unroll
    for (int n = 0; n < 4; ++n) bcol[n] = bias[n0 + wn * 64 + n * 16 + l15];
  }
  if (MODE == 1) {                      // fp32 out + residual, 4 passes of 64 rows
#pragma unroll
    for (int q = 0; q < 4; ++q) {
      if (q) __syncthreads();
      if (wm == (q >> 1)) {
#pragma unroll
        for (int i2 = 0; i2 < 4; ++i2)
#pragma unroll
          for (int n = 0; n < 4; ++n)
#pragma unroll
            for (int r = 0; r < 4; ++r) {
              const int lrow = i2 * 16 + lq * 4 + r;
              const int col = wn * 64 + n * 16 + l15;
              ((float*)lds)[lrow * 260 + col] = acc[(q & 1) * 4 + i2][n][r] + bcol[n];
            }
      }
      __syncthreads();
#pragma unroll
      for (int rep = 0; rep < 8; ++rep) {
        const int row = rep * 8 + (tid >> 6);
        const int colf = (tid & 63) * 4;
        float4 v = *(const float4*)((const float*)lds + row * 260 + colf);
        const size_t gidx = (size_t)(m0 + q * 64 + row) * N + n0 + colf;
        const float4 rv = *(const float4*)(res + gidx);
        v.x += rv.x; v.y += rv.y; v.z += rv.z; v.w += rv.w;
        *(float4*)((float*)Cout + gidx) = v;
      }
    }
  } else {                              // bf16 out, 2 passes of 128 rows
#pragma unroll
    for (int p = 0; p < 2; ++p) {
      if (p) __syncthreads();
      if (wm == p) {
#pragma unroll
        for (int i = 0; i < 8; ++i)
#pragma unroll
          for (int n = 0; n < 4; ++n)
#pragma unroll
            for (int r = 0; r < 4; ++r) {
              const int lrow = i * 16 + lq * 4 + r;
              const int col = wn * 64 + n * 16 + l15;
              float v = acc[i][n][r];
              if (MODE == 2) v = fmaxf(v + bcol[n], 0.f);
              ((unsigned short*)lds)[lrow * 264 + col] = f2bfu(v);
            }
      }
      __syncthreads();
#pragma unroll
      for (int rep = 0; rep < 8; ++rep) {
        const int row = rep * 16 + (tid >> 5);
        const int colc = (tid & 31) * 8;
        const uint4 v = *(const uint4*)((const unsigned short*)lds + row * 264 + colc);
        *(uint4*)((__hip_bfloat16*)Cout + (size_t)(m0 + p * 128 + row) * N + n0 + colc) = v;
      }
    }
  }
}

#undef PHASE
#undef PH_END
#undef STG

// ---------------- fused causal attention, one block per (b,h) --------------
__global__ __launch_bounds__(256, 2)
void attn_k(const __hip_bfloat16* __restrict__ qkv, __hip_bfloat16* __restrict__ cat) {
  __shared__ char sm[17408 + 34816 + 2048];
  char* stage = sm;                                 // QK staging 16KB / Vt [64][136]
  unsigned short* P = (unsigned short*)(sm + 17408);  // [128][136] bf16
  float* redm = (float*)(sm + 17408 + 34816);       // [2][128]
  float* reds = redm + 256;                         // [2][128]

  const int tid = threadIdx.x;
  const int w = tid >> 6, l = tid & 63;
  const int l15 = l & 15, lq = l >> 4;
  const int wm = w >> 1, wn = w & 1;
  const int bh = blockIdx.x, b = bh / NH, h = bh % NH;
  const unsigned short* qkvu = (const unsigned short*)qkv;
  const size_t tokbase = (size_t)b * SEQ;
  const int qcol = h * HDIM, kcol = CATD + h * HDIM, vcol = 2 * CATD + h * HDIM;

  f32x4 acc[4][4];
#pragma unroll
  for (int i = 0; i < 4; ++i)
#pragma unroll
    for (int j = 0; j < 4; ++j) acc[i][j] = {0.f, 0.f, 0.f, 0.f};

  // ---- phase A: S = Q K^T (K-loop over head dim, BK=32) ----
  for (int d0 = 0; d0 < HDIM; d0 += 32) {
#pragma unroll
    for (int i = 0; i < 4; ++i) {
      const int ch = w * 4 + i;
      const int rowloc = (ch & 7) * 16 + l15;
      const int colbase = (ch < 8 ? qcol : kcol) + d0 + lq * 8;
      gld_lds16(qkvu + (tokbase + rowloc) * QKVLD + colbase, stage + ch * 1024);
    }
    __syncthreads();
    bfrag af[4], bf[4];
#pragma unroll
    for (int i = 0; i < 4; ++i) {
      af[i] = *(const bfrag*)(stage + ((wm * 4 + i) * 64 + l) * 16);
      bf[i] = *(const bfrag*)(stage + 8192 + ((wn * 4 + i) * 64 + l) * 16);
    }
#pragma unroll
    for (int i = 0; i < 4; ++i)
#pragma unroll
      for (int j = 0; j < 4; ++j)
        acc[i][j] = __builtin_amdgcn_mfma_f32_16x16x32_bf16(af[i], bf[j], acc[i][j], 0, 0, 0);
    __syncthreads();
  }

  // ---- causal mask + scale + softmax stats ----
  const float scl = 0.03608439182435161f;  // 768^-0.5 (faithful to source)
  const int rowb = wm * 64 + lq * 4;
  const int colb = wn * 64 + l15;
  float rmax[4][4];
#pragma unroll
  for (int i = 0; i < 4; ++i)
#pragma unroll
    for (int r = 0; r < 4; ++r) {
      const int row = rowb + i * 16 + r;
      float m = -__builtin_inff();
#pragma unroll
      for (int j = 0; j < 4; ++j) {
        const int col = colb + j * 16;
        float sv = acc[i][j][r] * scl;
        if (col > row) sv = -__builtin_inff();
        acc[i][j][r] = sv;
        m = fmaxf(m, sv);
      }
#pragma unroll
      for (int d = 1; d < 16; d <<= 1) m = fmaxf(m, __shfl_xor(m, d, 64));
      rmax[i][r] = m;
    }
  if (l15 == 0) {
#pragma unroll
    for (int i = 0; i < 4; ++i)
#pragma unroll
      for (int r = 0; r < 4; ++r)
        redm[wn * 128 + rowb + i * 16 + r] = rmax[i][r];
  }
  __syncthreads();
  float rsum[4][4];
#pragma unroll
  for (int i = 0; i < 4; ++i)
#pragma unroll
    for (int r = 0; r < 4; ++r) {
      const int row = rowb + i * 16 + r;
      const float mfin = fmaxf(redm[row], redm[128 + row]);
      float sacc = 0.f;
#pragma unroll
      for (int j = 0; j < 4; ++j) {
        float p = __expf(acc[i][j][r] - mfin);   // exp(-inf - finite) = 0
        acc[i][j][r] = p;
        sacc += p;
      }
#pragma unroll
      for (int d = 1; d < 16; d <<= 1) sacc += __shfl_xor(sacc, d, 64);
      rsum[i][r] = sacc;
    }
  if (l15 == 0) {
#pragma unroll
    for (int i = 0; i < 4; ++i)
#pragma unroll
      for (int r = 0; r < 4; ++r)
        reds[wn * 128 + rowb + i * 16 + r] = rsum[i][r];
  }
  // unnormalized P -> LDS (C-layout -> A-layout round trip)
#pragma unroll
  for (int i = 0; i < 4; ++i)
#pragma unroll
    for (int j = 0; j < 4; ++j)
#pragma unroll
      for (int r = 0; r < 4; ++r)
        P[(rowb + i * 16 + r) * 136 + colb + j * 16] = f2bfu(acc[i][j][r]);
  __syncthreads();

  float invs[4][4];
#pragma unroll
  for (int i = 0; i < 4; ++i)
#pragma unroll
    for (int r = 0; r < 4; ++r) {
      const int row = rowb + i * 16 + r;
      invs[i][r] = 1.f / (reds[row] + reds[128 + row]);
    }

  // ---- phase B: O = P V, d in 4 tiles of 64 ----
  unsigned short* Vt = (unsigned short*)stage;   // [64][136] bf16
  for (int dt = 0; dt < 4; ++dt) {
#pragma unroll
    for (int p4 = 0; p4 < 4; ++p4) {
      const int slot = tid + p4 * 256;
      const int s = slot >> 3, dblk = slot & 7;
      uint4 val = *(const uint4*)(qkvu + (tokbase + s) * QKVLD + vcol + dt * 64 + dblk * 8);
      union { uint4 v; unsigned short u[8]; } uu; uu.v = val;
#pragma unroll
      for (int jj = 0; jj < 8; ++jj) Vt[(dblk * 8 + jj) * 136 + s] = uu.u[jj];
    }
    __syncthreads();
    f32x4 oacc[4][2];
#pragma unroll
    for (int i = 0; i < 4; ++i) { oacc[i][0] = {0.f,0.f,0.f,0.f}; oacc[i][1] = {0.f,0.f,0.f,0.f}; }
#pragma unroll
    for (int ks = 0; ks < 4; ++ks) {
      bfrag pf[4], vf[2];
#pragma unroll
      for (int i = 0; i < 4; ++i)
        pf[i] = *(const bfrag*)((char*)P + ((wm * 64 + i * 16 + l15) * 136 + ks * 32 + lq * 8) * 2);
#pragma unroll
      for (int j = 0; j < 2; ++j)
        vf[j] = *(const bfrag*)((char*)Vt + (((wn * 2 + j) * 16 + l15) * 136 + ks * 32 + lq * 8) * 2);
#pragma unroll
      for (int i = 0; i < 4; ++i)
#pragma unroll
        for (int j = 0; j < 2; ++j)
          oacc[i][j] = __builtin_amdgcn_mfma_f32_16x16x32_bf16(pf[i], vf[j], oacc[i][j], 0, 0, 0);
    }
#pragma unroll
    for (int i = 0; i < 4; ++i)
#pragma unroll
      for (int j = 0; j < 2; ++j)
#pragma unroll
        for (int r = 0; r < 4; ++r) {
          const int trow = rowb + i * 16 + r;
          const int dcol = dt * 64 + wn * 32 + j * 16 + l15;
          cat[(tokbase + trow) * CATD + h * HDIM + dcol] =
              __float2bfloat16(oacc[i][j][r] * invs[i][r]);
        }
    __syncthreads();
  }
}

// ---------------------------------------------------------------------------
extern "C" void kernel_launch(void* const* d_in, const int* in_sizes, int n_in,
                              void* d_out, int out_size, void* d_ws, size_t ws_size,
                              hipStream_t stream) {
  const float* x   = (const float*)d_in[0];
  const float* Wq  = (const float*)d_in[1];
  const float* Wk  = (const float*)d_in[2];
  const float* Wv  = (const float*)d_in[3];
  const float* Wo  = (const float*)d_in[4];
  const float* bo  = (const float*)d_in[5];
  const float* W1  = (const float*)d_in[6];
  const float* b1  = (const float*)d_in[7];
  const float* W2  = (const float*)d_in[8];
  const float* b2  = (const float*)d_in[9];
  const float* g1  = (const float*)d_in[10];
  const float* be1 = (const float*)d_in[11];
  const float* g2  = (const float*)d_in[12];
  const float* be2 = (const float*)d_in[13];
  float* out = (float*)d_out;

  // ---- workspace budget: weights (18 MB) + 3 chunk regions ----
  const size_t wbytes = (size_t)QKVLD * EMB * 2 + (size_t)EMB * CATD * 2 +
                        (size_t)FFD * EMB * 2 + (size_t)EMB * FFD * 2;
  int nc = 1;
  while (nc < 16 &&
         wbytes + (size_t)(NTOK / nc) * (9216 + 3072 + 3072) + 4096 > ws_size)
    nc <<= 1;
  const int Mc = NTOK / nc;       // tokens per chunk (divisible by 256)
  const int Bc = BATCH / nc;      // batches per chunk

  char* ws = (char*)d_ws;
  size_t off = 0;
  auto alloc = [&](size_t bytes) {
    char* p = ws + off;
    off += (bytes + 255) & ~(size_t)255;
    return p;
  };
  __hip_bfloat16* Wqkv_t = (__hip_bfloat16*)alloc((size_t)QKVLD * EMB * 2);
  __hip_bfloat16* Wo_t   = (__hip_bfloat16*)alloc((size_t)EMB * CATD * 2);
  __hip_bfloat16* W1_t   = (__hip_bfloat16*)alloc((size_t)FFD * EMB * 2);
  __hip_bfloat16* W2_t   = (__hip_bfloat16*)alloc((size_t)EMB * FFD * 2);
  char* R1 = (char*)alloc((size_t)Mc * 9216);
  char* R2 = (char*)alloc((size_t)Mc * 3072);
  char* R3 = (char*)alloc((size_t)Mc * 3072);

  // weight repack (inputs restored from pristine each call -> repack every call)
  repack_qkv<<<dim3(HDIM / 64, EMB / 64, 18), 256, 0, stream>>>(Wq, Wk, Wv, Wqkv_t);
  transpose_cast<<<dim3(EMB / 64, CATD / 64), 256, 0, stream>>>(Wo, Wo_t, CATD, EMB);
  transpose_cast<<<dim3(FFD / 64, EMB / 64), 256, 0, stream>>>(W1, W1_t, EMB, FFD);
  transpose_cast<<<dim3(EMB / 64, FFD / 64), 256, 0, stream>>>(W2, W2_t, FFD, EMB);

  for (int c = 0; c < nc; ++c) {
    const float* xc   = x + (size_t)c * Mc * EMB;
    float*       outc = out + (size_t)c * Mc * EMB;
    __hip_bfloat16* hbuf   = (__hip_bfloat16*)R3;
    __hip_bfloat16* qkv    = (__hip_bfloat16*)R1;
    __hip_bfloat16* cat    = (__hip_bfloat16*)R2;
    float*          attn_o = (float*)R3;
    __hip_bfloat16* h2     = (__hip_bfloat16*)R2;
    __hip_bfloat16* mlp1   = (__hip_bfloat16*)R1;

    ln_k<<<Mc / 4, 256, 0, stream>>>(xc, g1, be1, hbuf);
    gemm_k<0><<<dim3(QKVLD / 256, Mc / 256), 512, 0, stream>>>(
        hbuf, Wqkv_t, qkv, nullptr, nullptr, Mc, QKVLD, EMB);
    attn_k<<<Bc * NH, 256, 0, stream>>>(qkv, cat);
    gemm_k<1><<<dim3(EMB / 256, Mc / 256), 512, 0, stream>>>(
        cat, Wo_t, attn_o, bo, xc, Mc, EMB, CATD);
    ln_k<<<Mc / 4, 256, 0, stream>>>(attn_o, g2, be2, h2);
    gemm_k<2><<<dim3(FFD / 256, Mc / 256), 512, 0, stream>>>(
        h2, W1_t, mlp1, b1, nullptr, Mc, FFD, EMB);
    gemm_k<1><<<dim3(EMB / 256, Mc / 256), 512, 0, stream>>>(
        mlp1, W2_t, outc, b2, attn_o, Mc, EMB, FFD);
  }
}

// Round 2
// 2384.482 us; speedup vs baseline: 1.2446x; 1.0188x over previous
//
#include <hip/hip_runtime.h>
#include <hip/hip_bf16.h>

#define BATCH 512
#define SEQ   128
#define EMB   768
#define NH    6
#define HDIM  256
#define CATD  1536
#define FFD   3072
#define NTOK  (BATCH*SEQ)
#define QKVLD 4608

typedef __attribute__((ext_vector_type(8))) short bfrag;   // 8 bf16 = 4 VGPRs
typedef __attribute__((ext_vector_type(4))) float f32x4;

// async 16B global->LDS; LDS dest is wave-uniform base + lane*16
__device__ __forceinline__ void gld_lds16(const void* g, void* l) {
  __builtin_amdgcn_global_load_lds(
      (const __attribute__((address_space(1))) unsigned int*)g,
      (__attribute__((address_space(3))) unsigned int*)l, 16, 0, 0);
}

__device__ __forceinline__ unsigned short f2bfu(float f) {
  union { __hip_bfloat16 h; unsigned short u; } c;
  c.h = __float2bfloat16(f);
  return c.u;
}

// ---------------- weight repack: fp32 [R][C] -> bf16 [C][R] -----------------
__device__ __forceinline__ void transpose64(const float* in, int C,
                                            __hip_bfloat16* out, int R,
                                            int r0, int c0) {
  __shared__ float tile[64][65];
  const int tx = threadIdx.x & 63;
  const int ty = threadIdx.x >> 6;
#pragma unroll
  for (int i = 0; i < 16; ++i) {
    const int r = ty + i * 4;
    tile[r][tx] = in[(size_t)(r0 + r) * C + c0 + tx];
  }
  __syncthreads();
#pragma unroll
  for (int i = 0; i < 16; ++i) {
    const int cc = ty + i * 4;
    out[(size_t)(c0 + cc) * R + r0 + tx] = __float2bfloat16(tile[tx][cc]);
  }
}

__global__ __launch_bounds__(256) void transpose_cast(const float* __restrict__ in,
                                                      __hip_bfloat16* __restrict__ out,
                                                      int R, int C) {
  transpose64(in, C, out, R, blockIdx.y * 64, blockIdx.x * 64);
}

// Wq/Wk/Wv [H][E][D] -> Wqkv_t [4608][768], row n = m*1536 + h*256 + d
__global__ __launch_bounds__(256) void repack_qkv(const float* __restrict__ Wq,
                                                  const float* __restrict__ Wk,
                                                  const float* __restrict__ Wv,
                                                  __hip_bfloat16* __restrict__ out) {
  const int z = blockIdx.z, m = z / NH, h = z % NH;
  const float* in = (m == 0 ? Wq : (m == 1 ? Wk : Wv)) + (size_t)h * EMB * HDIM;
  __hip_bfloat16* o = out + (size_t)(m * CATD + h * HDIM) * EMB;
  transpose64(in, HDIM, o, EMB, blockIdx.y * 64, blockIdx.x * 64);
}

// ---------------- LayerNorm: fp32 [rows][768] -> bf16 ----------------------
__global__ __launch_bounds__(256) void ln_k(const float* __restrict__ src,
                                            const float* __restrict__ gam,
                                            const float* __restrict__ bet,
                                            __hip_bfloat16* __restrict__ dst) {
  const int row = blockIdx.x * 4 + (threadIdx.x >> 6);
  const int l = threadIdx.x & 63;
  const float* x = src + (size_t)row * EMB;
  float4 v[3];
#pragma unroll
  for (int j = 0; j < 3; ++j) v[j] = *(const float4*)(x + j * 256 + l * 4);
  float s = 0.f, ss = 0.f;
#pragma unroll
  for (int j = 0; j < 3; ++j) {
    s  += v[j].x + v[j].y + v[j].z + v[j].w;
    ss += v[j].x * v[j].x + v[j].y * v[j].y + v[j].z * v[j].z + v[j].w * v[j].w;
  }
#pragma unroll
  for (int d = 1; d < 64; d <<= 1) { s += __shfl_xor(s, d, 64); ss += __shfl_xor(ss, d, 64); }
  const float mu = s * (1.f / EMB);
  const float var = ss * (1.f / EMB) - mu * mu;
  const float rs = rsqrtf(var + 1e-5f);
#pragma unroll
  for (int j = 0; j < 3; ++j) {
    float4 g4 = *(const float4*)(gam + j * 256 + l * 4);
    float4 b4 = *(const float4*)(bet + j * 256 + l * 4);
    ushort4 o;
    o.x = f2bfu((v[j].x - mu) * rs * g4.x + b4.x);
    o.y = f2bfu((v[j].y - mu) * rs * g4.y + b4.y);
    o.z = f2bfu((v[j].z - mu) * rs * g4.z + b4.z);
    o.w = f2bfu((v[j].w - mu) * rs * g4.w + b4.w);
    *(ushort4*)((unsigned short*)dst + (size_t)row * EMB + j * 256 + l * 4) = o;
  }
}

// ---------------- GEMM: C[M][N] = A[M][K](bf16) * Bt[N][K](bf16) -----------
// 256x256 tile, BK=64, 8 waves (2M x 4N), 512 threads, 128 KiB LDS dbuf.
// Fragment-ordered staging: global_load_lds dest linear AND ds_read_b128
// conflict-free by construction (verified: SQ_LDS_BANK_CONFLICT == 0).
// m201-faithful phase schedule: each phase = {ds_read regs || STG issue}
// -> barrier -> lgkmcnt(0) -> setprio(1) 16xMFMA setprio(0) -> barrier.
// ds_read latency hides under barrier-arrival; MFMA starts immediately.
// Validity: vmcnt(4) moved to the TAIL of tile kt (before ph3's MFMA
// barrier) certifying tile kt+1 s0+s1 staged (newest 4 outstanding = kt+2
// s0). At kt=kIters-2 no kt+2 prefetch exists -> drain vmcnt(0) there.
// s0 chunks of a buffer are dead after phase 1 (both M-halves read A s0,
// B s0 re-read per half), so phases 2-3 prefetch kt+2 s0 into the CURRENT
// buffer while phases 0-1 prefetch kt+1 s1 into the other.
// MODE 0: C bf16 = acc ; MODE 1: C f32 = acc+bias+res ; MODE 2: bf16 relu(acc+bias)
#define PH_DS(S, MH)                                                         \
    bfrag af[4], bv[4];                                                      \
    {                                                                        \
      const char* Ab = cbuf + ((S)*16 + wm*8 + (MH)*4) * 1024 + l * 16;      \
      const char* Bb = cbuf + 32768 + ((S)*16 + wn*4) * 1024 + l * 16;       \
      _Pragma("unroll")                                                      \
      for (int i = 0; i < 4; ++i) af[i] = *(const bfrag*)(Ab + i * 1024);    \
      _Pragma("unroll")                                                      \
      for (int n = 0; n < 4; ++n) bv[n] = *(const bfrag*)(Bb + n * 1024);    \
    }

#define PH_MFMA(MH)                                                          \
    __builtin_amdgcn_s_barrier();                                            \
    asm volatile("s_waitcnt lgkmcnt(0)" ::: "memory");                       \
    __builtin_amdgcn_s_setprio(1);                                           \
    _Pragma("unroll")                                                        \
    for (int i = 0; i < 4; ++i)                                              \
      _Pragma("unroll")                                                      \
      for (int n = 0; n < 4; ++n)                                            \
        acc[(MH)*4 + i][n] = __builtin_amdgcn_mfma_f32_16x16x32_bf16(        \
            af[i], bv[n], acc[(MH)*4 + i][n], 0, 0, 0);                      \
    __builtin_amdgcn_s_setprio(0);                                           \
    __builtin_amdgcn_s_barrier();

#define STG(p, koff, dstoff) gld_lds16((p) + (koff), lds + (dstoff))

template <int MODE>
__global__ __launch_bounds__(512, 2)
void gemm_k(const __hip_bfloat16* __restrict__ A, const __hip_bfloat16* __restrict__ Bt,
            void* __restrict__ Cout, const float* __restrict__ bias,
            const float* __restrict__ res, int M, int N, int K) {
  __shared__ char lds[131072];          // 2 x (A 32KB + B 32KB); epilogue reuses
  const int tid = threadIdx.x;
  const int w = tid >> 6, l = tid & 63;
  const int l15 = l & 15, lq = l >> 4;
  const int wm = w >> 2, wn = w & 3;

  // XCD-aware bijective block swizzle (all grids divisible by 8)
  const int nwg = gridDim.x * gridDim.y;
  const int orig = blockIdx.y * gridDim.x + blockIdx.x;
  const int cpx = nwg >> 3;
  const int sw = (orig & 7) * cpx + (orig >> 3);
  const int n0 = (sw % gridDim.x) * 256;
  const int m0 = (sw / gridDim.x) * 256;

  const unsigned short* Au = (const unsigned short*)A;
  const unsigned short* Bu = (const unsigned short*)Bt;
  // per-lane staging sources; chunk rb covers rows rb*16+l15, lane part lq*8
  const unsigned short* pA_lo = Au + (size_t)(m0 + w * 16 + l15) * K + lq * 8;
  const unsigned short* pA_hi = Au + (size_t)(m0 + 128 + w * 16 + l15) * K + lq * 8;
  const unsigned short* pB_lo = Bu + (size_t)(n0 + w * 16 + l15) * K + lq * 8;
  const unsigned short* pB_hi = Bu + (size_t)(n0 + 128 + w * 16 + l15) * K + lq * 8;

  f32x4 acc[8][4];
#pragma unroll
  for (int i = 0; i < 8; ++i)
#pragma unroll
    for (int n = 0; n < 4; ++n) acc[i][n] = {0.f, 0.f, 0.f, 0.f};

  const int kIters = K >> 6;            // K/64, always >= 12 here

  // prologue: tile0 (s0+s1) -> buf0, tile1 s0 -> buf1
  STG(pA_lo, 0,  (0 + w) * 1024);
  STG(pA_hi, 0,  (8 + w) * 1024);
  STG(pB_lo, 0,  32768 + (0 + w) * 1024);
  STG(pB_hi, 0,  32768 + (8 + w) * 1024);
  STG(pA_lo, 32, (16 + w) * 1024);
  STG(pA_hi, 32, (24 + w) * 1024);
  STG(pB_lo, 32, 32768 + (16 + w) * 1024);
  STG(pB_hi, 32, 32768 + (24 + w) * 1024);
  STG(pA_lo, 64, 65536 + (0 + w) * 1024);
  STG(pA_hi, 64, 65536 + (8 + w) * 1024);
  STG(pB_lo, 64, 65536 + 32768 + (0 + w) * 1024);
  STG(pB_hi, 64, 65536 + 32768 + (8 + w) * 1024);
  // tile0 fully staged (newest 4 = tile1 s0 may stay in flight)
  asm volatile("s_waitcnt vmcnt(4)" ::: "memory");
  __builtin_amdgcn_s_barrier();

  for (int kt = 0; kt < kIters; ++kt) {
    const int cOff = (kt & 1) * 65536;
    const int nOff = cOff ^ 65536;
    const char* cbuf = lds + cOff;
    const bool pre1 = (kt + 1 < kIters);   // tile kt+1 s1 -> other buffer
    const bool pre2 = (kt + 2 < kIters);   // tile kt+2 s0 -> current buffer
    const int k1 = (kt + 1) * 64 + 32;
    const int k2 = (kt + 2) * 64;

    { // ---- phase 0: s=0, rows lo ----
      PH_DS(0, 0);
      if (pre1) {
        STG(pA_lo, k1, nOff + (16 + w) * 1024);
        STG(pB_lo, k1, nOff + 32768 + (16 + w) * 1024);
      }
      PH_MFMA(0);
    }
    { // ---- phase 1: s=0, rows hi ----
      PH_DS(0, 1);
      if (pre1) {
        STG(pA_hi, k1, nOff + (24 + w) * 1024);
        STG(pB_hi, k1, nOff + 32768 + (24 + w) * 1024);
      }
      PH_MFMA(1);                           // after this, cbuf s0 is dead
    }
    { // ---- phase 2: s=1, rows lo ----
      PH_DS(1, 0);
      if (pre2) {
        STG(pA_lo, k2, cOff + (0 + w) * 1024);
        STG(pB_lo, k2, cOff + 32768 + (0 + w) * 1024);
      }
      PH_MFMA(0);
    }
    { // ---- phase 3: s=1, rows hi ----
      PH_DS(1, 1);
      if (pre2) {
        STG(pA_hi, k2, cOff + (8 + w) * 1024);
        STG(pB_hi, k2, cOff + 32768 + (8 + w) * 1024);
        // certify tile kt+1 fully staged; newest 4 = kt+2 s0 stay in flight
        asm volatile("s_waitcnt vmcnt(4)" ::: "memory");
      } else {
        asm volatile("s_waitcnt vmcnt(0)" ::: "memory");
      }
      PH_MFMA(1);                           // cbuf s1 dead -> reusable next iter
    }
  }

  // ---- epilogue: acc (+bias/relu/res) -> LDS -> coalesced stores ----
  float bcol[4];
  if (MODE != 0) {
#pragma unroll
    for (int n = 0; n < 4; ++n) bcol[n] = bias[n0 + wn * 64 + n * 16 + l15];
  }
  if (MODE == 1) {                      // fp32 out + residual, 4 passes of 64 rows
#pragma unroll
    for (int q = 0; q < 4; ++q) {
      if (q) __syncthreads();
      if (wm == (q >> 1)) {
#pragma unroll
        for (int i2 = 0; i2 < 4; ++i2)
#pragma unroll
          for (int n = 0; n < 4; ++n)
#pragma unroll
            for (int r = 0; r < 4; ++r) {
              const int lrow = i2 * 16 + lq * 4 + r;
              const int col = wn * 64 + n * 16 + l15;
              ((float*)lds)[lrow * 260 + col] = acc[(q & 1) * 4 + i2][n][r] + bcol[n];
            }
      }
      __syncthreads();
#pragma unroll
      for (int rep = 0; rep < 8; ++rep) {
        const int row = rep * 8 + (tid >> 6);
        const int colf = (tid & 63) * 4;
        float4 v = *(const float4*)((const float*)lds + row * 260 + colf);
        const size_t gidx = (size_t)(m0 + q * 64 + row) * N + n0 + colf;
        const float4 rv = *(const float4*)(res + gidx);
        v.x += rv.x; v.y += rv.y; v.z += rv.z; v.w += rv.w;
        *(float4*)((float*)Cout + gidx) = v;
      }
    }
  } else {                              // bf16 out, 2 passes of 128 rows
#pragma unroll
    for (int p = 0; p < 2; ++p) {
      if (p) __syncthreads();
      if (wm == p) {
#pragma unroll
        for (int i = 0; i < 8; ++i)
#pragma unroll
          for (int n = 0; n < 4; ++n)
#pragma unroll
            for (int r = 0; r < 4; ++r) {
              const int lrow = i * 16 + lq * 4 + r;
              const int col = wn * 64 + n * 16 + l15;
              float v = acc[i][n][r];
              if (MODE == 2) v = fmaxf(v + bcol[n], 0.f);
              ((unsigned short*)lds)[lrow * 264 + col] = f2bfu(v);
            }
      }
      __syncthreads();
#pragma unroll
      for (int rep = 0; rep < 8; ++rep) {
        const int row = rep * 16 + (tid >> 5);
        const int colc = (tid & 31) * 8;
        const uint4 v = *(const uint4*)((const unsigned short*)lds + row * 264 + colc);
        *(uint4*)((__hip_bfloat16*)Cout + (size_t)(m0 + p * 128 + row) * N + n0 + colc) = v;
      }
    }
  }
}

#undef PH_DS
#undef PH_MFMA
#undef STG

// ---------------- fused causal attention, one block per (b,h) --------------
__global__ __launch_bounds__(256, 2)
void attn_k(const __hip_bfloat16* __restrict__ qkv, __hip_bfloat16* __restrict__ cat) {
  __shared__ char sm[17408 + 34816 + 2048];
  char* stage = sm;                                 // QK staging 16KB / Vt [64][136]
  unsigned short* P = (unsigned short*)(sm + 17408);  // [128][136] bf16
  float* redm = (float*)(sm + 17408 + 34816);       // [2][128]
  float* reds = redm + 256;                         // [2][128]

  const int tid = threadIdx.x;
  const int w = tid >> 6, l = tid & 63;
  const int l15 = l & 15, lq = l >> 4;
  const int wm = w >> 1, wn = w & 1;
  const int bh = blockIdx.x, b = bh / NH, h = bh % NH;
  const unsigned short* qkvu = (const unsigned short*)qkv;
  const size_t tokbase = (size_t)b * SEQ;
  const int qcol = h * HDIM, kcol = CATD + h * HDIM, vcol = 2 * CATD + h * HDIM;

  f32x4 acc[4][4];
#pragma unroll
  for (int i = 0; i < 4; ++i)
#pragma unroll
    for (int j = 0; j < 4; ++j) acc[i][j] = {0.f, 0.f, 0.f, 0.f};

  // ---- phase A: S = Q K^T (K-loop over head dim, BK=32) ----
  for (int d0 = 0; d0 < HDIM; d0 += 32) {
#pragma unroll
    for (int i = 0; i < 4; ++i) {
      const int ch = w * 4 + i;
      const int rowloc = (ch & 7) * 16 + l15;
      const int colbase = (ch < 8 ? qcol : kcol) + d0 + lq * 8;
      gld_lds16(qkvu + (tokbase + rowloc) * QKVLD + colbase, stage + ch * 1024);
    }
    __syncthreads();
    bfrag af[4], bf[4];
#pragma unroll
    for (int i = 0; i < 4; ++i) {
      af[i] = *(const bfrag*)(stage + ((wm * 4 + i) * 64 + l) * 16);
      bf[i] = *(const bfrag*)(stage + 8192 + ((wn * 4 + i) * 64 + l) * 16);
    }
#pragma unroll
    for (int i = 0; i < 4; ++i)
#pragma unroll
      for (int j = 0; j < 4; ++j)
        acc[i][j] = __builtin_amdgcn_mfma_f32_16x16x32_bf16(af[i], bf[j], acc[i][j], 0, 0, 0);
    __syncthreads();
  }

  // ---- causal mask + scale + softmax stats ----
  const float scl = 0.03608439182435161f;  // 768^-0.5 (faithful to source)
  const int rowb = wm * 64 + lq * 4;
  const int colb = wn * 64 + l15;
  float rmax[4][4];
#pragma unroll
  for (int i = 0; i < 4; ++i)
#pragma unroll
    for (int r = 0; r < 4; ++r) {
      const int row = rowb + i * 16 + r;
      float m = -__builtin_inff();
#pragma unroll
      for (int j = 0; j < 4; ++j) {
        const int col = colb + j * 16;
        float sv = acc[i][j][r] * scl;
        if (col > row) sv = -__builtin_inff();
        acc[i][j][r] = sv;
        m = fmaxf(m, sv);
      }
#pragma unroll
      for (int d = 1; d < 16; d <<= 1) m = fmaxf(m, __shfl_xor(m, d, 64));
      rmax[i][r] = m;
    }
  if (l15 == 0) {
#pragma unroll
    for (int i = 0; i < 4; ++i)
#pragma unroll
      for (int r = 0; r < 4; ++r)
        redm[wn * 128 + rowb + i * 16 + r] = rmax[i][r];
  }
  __syncthreads();
  float rsum[4][4];
#pragma unroll
  for (int i = 0; i < 4; ++i)
#pragma unroll
    for (int r = 0; r < 4; ++r) {
      const int row = rowb + i * 16 + r;
      const float mfin = fmaxf(redm[row], redm[128 + row]);
      float sacc = 0.f;
#pragma unroll
      for (int j = 0; j < 4; ++j) {
        float p = __expf(acc[i][j][r] - mfin);   // exp(-inf - finite) = 0
        acc[i][j][r] = p;
        sacc += p;
      }
#pragma unroll
      for (int d = 1; d < 16; d <<= 1) sacc += __shfl_xor(sacc, d, 64);
      rsum[i][r] = sacc;
    }
  if (l15 == 0) {
#pragma unroll
    for (int i = 0; i < 4; ++i)
#pragma unroll
      for (int r = 0; r < 4; ++r)
        reds[wn * 128 + rowb + i * 16 + r] = rsum[i][r];
  }
  // unnormalized P -> LDS (C-layout -> A-layout round trip)
#pragma unroll
  for (int i = 0; i < 4; ++i)
#pragma unroll
    for (int j = 0; j < 4; ++j)
#pragma unroll
      for (int r = 0; r < 4; ++r)
        P[(rowb + i * 16 + r) * 136 + colb + j * 16] = f2bfu(acc[i][j][r]);
  __syncthreads();

  float invs[4][4];
#pragma unroll
  for (int i = 0; i < 4; ++i)
#pragma unroll
    for (int r = 0; r < 4; ++r) {
      const int row = rowb + i * 16 + r;
      invs[i][r] = 1.f / (reds[row] + reds[128 + row]);
    }

  // ---- phase B: O = P V, d in 4 tiles of 64 ----
  unsigned short* Vt = (unsigned short*)stage;   // [64][136] bf16
  for (int dt = 0; dt < 4; ++dt) {
#pragma unroll
    for (int p4 = 0; p4 < 4; ++p4) {
      const int slot = tid + p4 * 256;
      const int s = slot >> 3, dblk = slot & 7;
      uint4 val = *(const uint4*)(qkvu + (tokbase + s) * QKVLD + vcol + dt * 64 + dblk * 8);
      union { uint4 v; unsigned short u[8]; } uu; uu.v = val;
#pragma unroll
      for (int jj = 0; jj < 8; ++jj) Vt[(dblk * 8 + jj) * 136 + s] = uu.u[jj];
    }
    __syncthreads();
    f32x4 oacc[4][2];
#pragma unroll
    for (int i = 0; i < 4; ++i) { oacc[i][0] = {0.f,0.f,0.f,0.f}; oacc[i][1] = {0.f,0.f,0.f,0.f}; }
#pragma unroll
    for (int ks = 0; ks < 4; ++ks) {
      bfrag pf[4], vf[2];
#pragma unroll
      for (int i = 0; i < 4; ++i)
        pf[i] = *(const bfrag*)((char*)P + ((wm * 64 + i * 16 + l15) * 136 + ks * 32 + lq * 8) * 2);
#pragma unroll
      for (int j = 0; j < 2; ++j)
        vf[j] = *(const bfrag*)((char*)Vt + (((wn * 2 + j) * 16 + l15) * 136 + ks * 32 + lq * 8) * 2);
#pragma unroll
      for (int i = 0; i < 4; ++i)
#pragma unroll
        for (int j = 0; j < 2; ++j)
          oacc[i][j] = __builtin_amdgcn_mfma_f32_16x16x32_bf16(pf[i], vf[j], oacc[i][j], 0, 0, 0);
    }
#pragma unroll
    for (int i = 0; i < 4; ++i)
#pragma unroll
      for (int j = 0; j < 2; ++j)
#pragma unroll
        for (int r = 0; r < 4; ++r) {
          const int trow = rowb + i * 16 + r;
          const int dcol = dt * 64 + wn * 32 + j * 16 + l15;
          cat[(tokbase + trow) * CATD + h * HDIM + dcol] =
              __float2bfloat16(oacc[i][j][r] * invs[i][r]);
        }
    __syncthreads();
  }
}

// ---------------------------------------------------------------------------
extern "C" void kernel_launch(void* const* d_in, const int* in_sizes, int n_in,
                              void* d_out, int out_size, void* d_ws, size_t ws_size,
                              hipStream_t stream) {
  const float* x   = (const float*)d_in[0];
  const float* Wq  = (const float*)d_in[1];
  const float* Wk  = (const float*)d_in[2];
  const float* Wv  = (const float*)d_in[3];
  const float* Wo  = (const float*)d_in[4];
  const float* bo  = (const float*)d_in[5];
  const float* W1  = (const float*)d_in[6];
  const float* b1  = (const float*)d_in[7];
  const float* W2  = (const float*)d_in[8];
  const float* b2  = (const float*)d_in[9];
  const float* g1  = (const float*)d_in[10];
  const float* be1 = (const float*)d_in[11];
  const float* g2  = (const float*)d_in[12];
  const float* be2 = (const float*)d_in[13];
  float* out = (float*)d_out;

  // ---- workspace budget: weights (18 MB) + 3 chunk regions ----
  const size_t wbytes = (size_t)QKVLD * EMB * 2 + (size_t)EMB * CATD * 2 +
                        (size_t)FFD * EMB * 2 + (size_t)EMB * FFD * 2;
  int nc = 1;
  while (nc < 16 &&
         wbytes + (size_t)(NTOK / nc) * (9216 + 3072 + 3072) + 4096 > ws_size)
    nc <<= 1;
  const int Mc = NTOK / nc;       // tokens per chunk (divisible by 256)
  const int Bc = BATCH / nc;      // batches per chunk

  char* ws = (char*)d_ws;
  size_t off = 0;
  auto alloc = [&](size_t bytes) {
    char* p = ws + off;
    off += (bytes + 255) & ~(size_t)255;
    return p;
  };
  __hip_bfloat16* Wqkv_t = (__hip_bfloat16*)alloc((size_t)QKVLD * EMB * 2);
  __hip_bfloat16* Wo_t   = (__hip_bfloat16*)alloc((size_t)EMB * CATD * 2);
  __hip_bfloat16* W1_t   = (__hip_bfloat16*)alloc((size_t)FFD * EMB * 2);
  __hip_bfloat16* W2_t   = (__hip_bfloat16*)alloc((size_t)EMB * FFD * 2);
  char* R1 = (char*)alloc((size_t)Mc * 9216);
  char* R2 = (char*)alloc((size_t)Mc * 3072);
  char* R3 = (char*)alloc((size_t)Mc * 3072);

  // weight repack (inputs restored from pristine each call -> repack every call)
  repack_qkv<<<dim3(HDIM / 64, EMB / 64, 18), 256, 0, stream>>>(Wq, Wk, Wv, Wqkv_t);
  transpose_cast<<<dim3(EMB / 64, CATD / 64), 256, 0, stream>>>(Wo, Wo_t, CATD, EMB);
  transpose_cast<<<dim3(FFD / 64, EMB / 64), 256, 0, stream>>>(W1, W1_t, EMB, FFD);
  transpose_cast<<<dim3(EMB / 64, FFD / 64), 256, 0, stream>>>(W2, W2_t, FFD, EMB);

  for (int c = 0; c < nc; ++c) {
    const float* xc   = x + (size_t)c * Mc * EMB;
    float*       outc = out + (size_t)c * Mc * EMB;
    __hip_bfloat16* hbuf   = (__hip_bfloat16*)R3;
    __hip_bfloat16* qkv    = (__hip_bfloat16*)R1;
    __hip_bfloat16* cat    = (__hip_bfloat16*)R2;
    float*          attn_o = (float*)R3;
    __hip_bfloat16* h2     = (__hip_bfloat16*)R2;
    __hip_bfloat16* mlp1   = (__hip_bfloat16*)R1;

    ln_k<<<Mc / 4, 256, 0, stream>>>(xc, g1, be1, hbuf);
    gemm_k<0><<<dim3(QKVLD / 256, Mc / 256), 512, 0, stream>>>(
        hbuf, Wqkv_t, qkv, nullptr, nullptr, Mc, QKVLD, EMB);
    attn_k<<<Bc * NH, 256, 0, stream>>>(qkv, cat);
    gemm_k<1><<<dim3(EMB / 256, Mc / 256), 512, 0, stream>>>(
        cat, Wo_t, attn_o, bo, xc, Mc, EMB, CATD);
    ln_k<<<Mc / 4, 256, 0, stream>>>(attn_o, g2, be2, h2);
    gemm_k<2><<<dim3(FFD / 256, Mc / 256), 512, 0, stream>>>(
        h2, W1_t, mlp1, b1, nullptr, Mc, FFD, EMB);
    gemm_k<1><<<dim3(EMB / 256, Mc / 256), 512, 0, stream>>>(
        mlp1, W2_t, outc, b2, attn_o, Mc, EMB, FFD);
  }
}